// Round 9
// baseline (276.167 us; speedup 1.0000x reference)
//
#include <hip/hip_runtime.h>
#include <hip/hip_bf16.h>

typedef unsigned short u16;
typedef __attribute__((ext_vector_type(8))) __bf16 bf16x8;
typedef __attribute__((ext_vector_type(4))) float f32x4;
typedef __attribute__((ext_vector_type(4))) unsigned int u32x4;

#define CC 1024
#define LL 4096
#define NB 8

#define VMCNT(n) asm volatile("s_waitcnt vmcnt(" #n ")" ::: "memory")
#define LGKMC(n) asm volatile("s_waitcnt lgkmcnt(" #n ")" ::: "memory")
#define BAR()    asm volatile("s_barrier" ::: "memory")

__device__ __forceinline__ u16 f2bf(float f) {
  union { float f; unsigned u; } v; v.f = f;
  unsigned u = v.u;
  return (u16)((u + 0x7fffu + ((u >> 16) & 1u)) >> 16);
}

// native hardware cvt (RTNE)
__device__ __forceinline__ u16 bfc(float f) {
  __bf16 h = (__bf16)f;
  return __builtin_bit_cast(u16, h);
}

__device__ __forceinline__ void gload_lds16(const void* g, void* l) {
  __builtin_amdgcn_global_load_lds(
      (const __attribute__((address_space(1))) void*)g,
      (__attribute__((address_space(3))) void*)l, 16, 0, 0);
}

// ---------------------------------------------------------------------------
// Fused depthwise conv (K=7, pad=3): q,k row-major [b,c,l] bf16, v transposed
// [b,l,c] bf16. Tile: 64 channels x 128 positions; thread = 1ch x 32pos.
// x read straight to regs (10x dwordx4). LDS only for the v transpose
// (group-XOR swizzled, 0 conflicts). Barrier = lgkmcnt(0)+s_barrier ONLY —
// __syncthreads would drain vmcnt(0), serializing the 8 q/k stores into the
// critical path (R8: 120us @2.5TB/s, latency-bound).
// ---------------------------------------------------------------------------
__global__ __launch_bounds__(256) void dwconv_qkv(
    const float* __restrict__ x, const float* __restrict__ qw,
    const float* __restrict__ kw, const float* __restrict__ vw,
    u16* __restrict__ qo, u16* __restrict__ ko, u16* __restrict__ vto)
{
  __shared__ u16 vs[128][68];
  const int t  = threadIdx.x;
  const int l0 = blockIdx.x << 7;   // 128-position tile
  const int c0 = blockIdx.y << 6;   // 64-channel tile
  const int b  = blockIdx.z;
  const int cc = t >> 2;            // channel within tile (0..63)
  const int g  = t & 3;             // 32-position group
  const int c  = c0 + cc;
  const float* xr = x + ((size_t)(b * CC + c)) * LL;
  const int p0 = l0 + (g << 5);

  float xv[40];                     // [p0-4, p0+36)
  if (l0 != 0 && l0 != LL - 128) {
    const float4* base = (const float4*)(xr + p0 - 4);
#pragma unroll
    for (int j = 0; j < 10; ++j) {
      float4 f = base[j];
      xv[4 * j + 0] = f.x; xv[4 * j + 1] = f.y;
      xv[4 * j + 2] = f.z; xv[4 * j + 3] = f.w;
    }
  } else {
#pragma unroll
    for (int i = 0; i < 40; ++i) {
      int gl = p0 - 4 + i;
      xv[i] = ((unsigned)gl < (unsigned)LL) ? xr[gl] : 0.f;
    }
  }

  float wq[7], wk[7], wv[7];
#pragma unroll
  for (int j = 0; j < 7; ++j) {
    wq[j] = qw[c * 7 + j]; wk[j] = kw[c * 7 + j]; wv[j] = vw[c * 7 + j];
  }

  const int wgrp = cc >> 4;         // == wave index; uniform per wave
  alignas(16) u16 qv[32], kv[32];
#pragma unroll
  for (int li = 0; li < 32; ++li) {
    float aq = 0.f, ak = 0.f, av = 0.f;
#pragma unroll
    for (int j = 0; j < 7; ++j) {
      float xf = xv[li + 1 + j];    // = x[p0 + li - 3 + j]
      aq = fmaf(xf, wq[j], aq);
      ak = fmaf(xf, wk[j], ak);
      av = fmaf(xf, wv[j], av);
    }
    qv[li] = bfc(aq);
    kv[li] = bfc(ak);
    vs[(g << 5) + li][(cc & 15) + ((wgrp ^ g) << 4)] = bfc(av);
  }
  size_t qoff = ((size_t)(b * CC + c)) * LL + p0;
#pragma unroll
  for (int h = 0; h < 4; ++h) {
    ((u32x4*)(qo + qoff))[h] = ((const u32x4*)qv)[h];
    ((u32x4*)(ko + qoff))[h] = ((const u32x4*)kv)[h];
  }

  LGKMC(0);                         // v LDS writes visible; q/k stores stay in flight
  BAR();
  const int ll   = t >> 1;          // transpose-out row (0..127)
  const int half = t & 1;           // 32-channel half
  const int gll  = ll >> 5;
  alignas(16) u16 vr[32];
#pragma unroll
  for (int bb = 0; bb < 2; ++bb) {
    const int sb = ((half << 1) | bb) ^ gll;   // swizzled 16-ch block
#pragma unroll
    for (int j = 0; j < 16; ++j)
      vr[bb * 16 + j] = vs[ll][(sb << 4) + j];
  }
  size_t voff = ((size_t)(b * LL) + l0 + ll) * CC + c0 + (half << 5);
#pragma unroll
  for (int h = 0; h < 4; ++h)
    ((u32x4*)(vto + voff))[h] = ((const u32x4*)vr)[h];
}

// ---------------------------------------------------------------------------
// 256x256 NT bf16 GEMM, 4-phase/K-tile derived-waits pipeline (m201-class).
// C[m][n] = sum_k A[m][k]*B[n][k]. 512 thr = 8 waves (2M x 4N), 128x64/wave.
// BK=64; LDS = 2 dbuf x (A 256x64 + B 256x64) bf16 = 128 KB.
// One vmcnt(6) per K-tile; raw s_barrier only; XOR-swizzled staging (T2);
// setprio around MFMA clusters (T5); XCD-aware block decode (T1).
// R9: counted lgkm waits — q1/q2 wait lgkmcnt(4), leaving next-phase A/B
// prefetch ds_reads outstanding under the MFMA cluster. Safety: q2's wait
// forces all half0 reads before q3's half0 stage; q3's lgkmcnt(0) precedes
// q4's half1 stage.
// ---------------------------------------------------------------------------
__global__ __launch_bounds__(512, 2) void gemm256p(
    const u16* __restrict__ A, int lda, size_t sA,
    const u16* __restrict__ B, int ldb, size_t sB,
    float* __restrict__ C0, float* __restrict__ C1, int ldc, size_t sC,
    int K, int ksplit, int mapmode)
{
  __shared__ alignas(16) u16 lds[65536];   // 128 KB
  const int t    = threadIdx.x;
  const int lane = t & 63, wave = t >> 6;
  const int wrow = wave >> 2, wcol = wave & 3;
  int bx, by, z;
  if (mapmode == 0) {        // GEMM1: 256 blocks; XCD x <- batch-splits {x,x+8}
    int wg = blockIdx.x; z = wg & 15; int r = wg >> 4; bx = r & 3; by = r >> 2;
  } else {                   // GEMM2: 512 blocks; XCD x <- batch x, y-fastest
    int wg = blockIdx.x; z = wg & 7; by = (wg >> 3) & 3; bx = wg >> 5;
  }
  const int bm = by << 8, bn = bx << 8;
  const int batch = (ksplit == 2) ? (z >> 1) : z;
  const int split = (ksplit == 2) ? (z & 1) : 0;
  const int Ks    = (ksplit == 2) ? (K >> 1) : K;
  const u16* Ab = A + (size_t)batch * sA + (size_t)split * Ks;
  const u16* Bb = B + (size_t)batch * sB + (size_t)split * Ks;

  // --- staging pointers: chunk c = wave*2+i covers 8 rows x 128B
  const int srow = lane >> 3;
  const int scol = ((lane & 7) ^ srow) << 3;   // pre-swizzled source col
  const u16* pA[2][2]; const u16* pB[2][2];    // [half][i]
  int dstOff[2];
#pragma unroll
  for (int i = 0; i < 2; ++i) {
    int cch = wave * 2 + i;
    dstOff[i] = cch * 1024 + lane * 16;        // byte offset within 16KB half
    pA[0][i] = Ab + (size_t)(bm + cch * 8 + srow) * lda + scol;
    pA[1][i] = pA[0][i] + (size_t)128 * lda;
    pB[0][i] = Bb + (size_t)(bn + cch * 8 + srow) * ldb + scol;
    pB[1][i] = pB[0][i] + (size_t)128 * ldb;
  }
  // dbuf d byte base = d*65536; A half h at h*16384; B at 32768 + h*16384.

#define STGH(P, h, base, koff)                                            \
  do {                                                                    \
    gload_lds16(P[h][0] + (koff), (char*)lds + (base) + dstOff[0]);       \
    gload_lds16(P[h][1] + (koff), (char*)lds + (base) + dstOff[1]);       \
  } while (0)

  // --- fragment read offsets
  const int r15 = lane & 15, kq = lane >> 4, swz = r15 & 7;
  int rowA[8], rowB[4], colK[2];
#pragma unroll
  for (int m = 0; m < 8; ++m) rowA[m] = (wrow * 128 + m * 16 + r15) * 128;
#pragma unroll
  for (int n = 0; n < 4; ++n) rowB[n] = 32768 + (wcol * 64 + n * 16 + r15) * 128;
#pragma unroll
  for (int s = 0; s < 2; ++s) colK[s] = (((s * 4 + kq) ^ swz)) << 4;

  f32x4 acc[8][4];
#pragma unroll
  for (int i = 0; i < 8; ++i)
#pragma unroll
    for (int j = 0; j < 4; ++j) acc[i][j] = f32x4{0.f, 0.f, 0.f, 0.f};

  const int NT = Ks >> 6;

  // --- prologue: tile0 -> dbuf0 (all), tile1 -> dbuf1 (A0,A1,B0)
  STGH(pA, 0, 0, 0);            STGH(pA, 1, 16384, 0);
  STGH(pB, 0, 32768, 0);        STGH(pB, 1, 49152, 0);
  STGH(pA, 0, 65536 + 0, 64);   STGH(pA, 1, 65536 + 16384, 64);
  STGH(pB, 0, 65536 + 32768, 64);
  VMCNT(6);
  BAR();

  const char* L = (const char*)lds;
  for (int tt = 0; tt < NT; ++tt) {
    const int d = tt & 1;
    const int dbase = d << 16, sbase = (d ^ 1) << 16;
    const int kN1 = (tt + 1) << 6, kN2 = (tt + 2) << 6;
    // ---- q1: reads {a0,b0} then prefetch aK1a; stage B1(t+1); MFMA (m0-3,k0)
    bf16x8 a0[4], aK1a[4], b0[4];
#pragma unroll
    for (int m = 0; m < 4; ++m) a0[m] = *(const bf16x8*)(L + dbase + rowA[m] + colK[0]);
#pragma unroll
    for (int n = 0; n < 4; ++n) b0[n] = *(const bf16x8*)(L + dbase + rowB[n] + colK[0]);
    if (tt + 1 < NT) STGH(pB, 1, sbase + 49152, kN1);
#pragma unroll
    for (int m = 0; m < 4; ++m) aK1a[m] = *(const bf16x8*)(L + dbase + rowA[m] + colK[1]);
    LGKMC(4);                          // a0,b0 forced; aK1a may stay in flight
    __builtin_amdgcn_sched_barrier(0);
    __builtin_amdgcn_s_setprio(1);
#pragma unroll
    for (int m = 0; m < 4; ++m)
#pragma unroll
      for (int n = 0; n < 4; ++n)
        acc[m][n] = __builtin_amdgcn_mfma_f32_16x16x32_bf16(a0[m], b0[n], acc[m][n], 0, 0, 0);
    __builtin_amdgcn_s_setprio(0);
    // ---- q2: reads a4 then prefetch aK1b; MFMA (m4-7, k0)
    bf16x8 a4[4], aK1b[4];
#pragma unroll
    for (int m = 0; m < 4; ++m) a4[m] = *(const bf16x8*)(L + dbase + rowA[m + 4] + colK[0]);
#pragma unroll
    for (int m = 0; m < 4; ++m) aK1b[m] = *(const bf16x8*)(L + dbase + rowA[m + 4] + colK[1]);
    LGKMC(4);                          // aK1a,a4 forced; aK1b may stay in flight
    __builtin_amdgcn_sched_barrier(0);
    __builtin_amdgcn_s_setprio(1);
#pragma unroll
    for (int m = 0; m < 4; ++m)
#pragma unroll
      for (int n = 0; n < 4; ++n)
        acc[m + 4][n] = __builtin_amdgcn_mfma_f32_16x16x32_bf16(a4[m], b0[n], acc[m + 4][n], 0, 0, 0);
    __builtin_amdgcn_s_setprio(0);
    BAR();                     // all A(t)-half0 reads forced (q2 wait) -> q3 stage safe
    // ---- q3: B k1; stage A0(t+2) into THIS dbuf; MFMA (m0-3, k1)
    bf16x8 b1[4];
#pragma unroll
    for (int n = 0; n < 4; ++n) b1[n] = *(const bf16x8*)(L + dbase + rowB[n] + colK[1]);
    if (tt + 2 < NT) STGH(pA, 0, dbase + 0, kN2);
    LGKMC(0);                          // b1 + aK1b all complete
    __builtin_amdgcn_sched_barrier(0);
    __builtin_amdgcn_s_setprio(1);
#pragma unroll
    for (int m = 0; m < 4; ++m)
#pragma unroll
      for (int n = 0; n < 4; ++n)
        acc[m][n] = __builtin_amdgcn_mfma_f32_16x16x32_bf16(aK1a[m], b1[n], acc[m][n], 0, 0, 0);
    __builtin_amdgcn_s_setprio(0);
    BAR();                     // all B(t) reads done -> q4 stages safe
    // ---- q4: stage A1,B0(t+2); MFMA (m4-7, k1); vmcnt; barrier
    if (tt + 2 < NT) { STGH(pA, 1, dbase + 16384, kN2); STGH(pB, 0, dbase + 32768, kN2); }
    __builtin_amdgcn_s_setprio(1);
#pragma unroll
    for (int m = 0; m < 4; ++m)
#pragma unroll
      for (int n = 0; n < 4; ++n)
        acc[m + 4][n] = __builtin_amdgcn_mfma_f32_16x16x32_bf16(aK1b[m], b1[n], acc[m + 4][n], 0, 0, 0);
    __builtin_amdgcn_s_setprio(0);
    if (tt < NT - 2) { VMCNT(6); } else { VMCNT(0); }
    BAR();                     // tile t+1 fully landed before next q1 reads
  }
#undef STGH

  float* Cb = (split ? C1 : C0) + (size_t)batch * sC;
  const int row0 = bm + wrow * 128 + kq * 4;
  const int col0 = bn + wcol * 64 + r15;
#pragma unroll
  for (int m = 0; m < 8; ++m)
#pragma unroll
    for (int n = 0; n < 4; ++n) {
      const int r   = row0 + m * 16;
      const int col = col0 + n * 16;
#pragma unroll
      for (int rr = 0; rr < 4; ++rr)
        Cb[(size_t)(r + rr) * ldc + col] = acc[m][n][rr];
    }
}

// ---------------------------------------------------------------------------
// Row softmax over fp32 [8192][1024]: sums split-K partials, scales 1/sqrt(C),
// writes bf16 attn in place (row stride stays 4096 B = 2048 u16).
// ---------------------------------------------------------------------------
__global__ __launch_bounds__(256) void softmax_rows(
    float* __restrict__ score, const float* __restrict__ part)
{
  __shared__ float rmax[4], rsum[4];
  const int t = threadIdx.x;
  const int lane = t & 63, wv = t >> 6;
  float* sp = score + ((size_t)blockIdx.x << 10);
  const float* pp = part + ((size_t)blockIdx.x << 10);
  float4 v = ((const float4*)sp)[t];
  float4 w = ((const float4*)pp)[t];
  const float scale = 0.03125f;   // 1/sqrt(1024)
  float a0 = (v.x + w.x) * scale, a1 = (v.y + w.y) * scale;
  float a2 = (v.z + w.z) * scale, a3 = (v.w + w.w) * scale;
  float m = fmaxf(fmaxf(a0, a1), fmaxf(a2, a3));
#pragma unroll
  for (int o = 1; o < 64; o <<= 1) m = fmaxf(m, __shfl_xor(m, o, 64));
  if (lane == 0) rmax[wv] = m;
  __syncthreads();
  m = fmaxf(fmaxf(rmax[0], rmax[1]), fmaxf(rmax[2], rmax[3]));
  float e0 = __expf(a0 - m), e1 = __expf(a1 - m);
  float e2 = __expf(a2 - m), e3 = __expf(a3 - m);
  float s = e0 + e1 + e2 + e3;
#pragma unroll
  for (int o = 1; o < 64; o <<= 1) s += __shfl_xor(s, o, 64);
  if (lane == 0) rsum[wv] = s;
  __syncthreads();
  s = rsum[0] + rsum[1] + rsum[2] + rsum[3];
  const float inv = 1.0f / s;
  union { u16 u[4]; uint2 p; } ob;
  ob.u[0] = f2bf(e0 * inv); ob.u[1] = f2bf(e1 * inv);
  ob.u[2] = f2bf(e2 * inv); ob.u[3] = f2bf(e3 * inv);
  *(uint2*)((u16*)sp + (t << 2)) = ob.p;
}

// ---------------------------------------------------------------------------
extern "C" void kernel_launch(void* const* d_in, const int* in_sizes, int n_in,
                              void* d_out, int out_size, void* d_ws, size_t ws_size,
                              hipStream_t stream) {
  const float* x  = (const float*)d_in[0];
  const float* qw = (const float*)d_in[1];
  const float* kw = (const float*)d_in[2];
  const float* vw = (const float*)d_in[3];
  float* out = (float*)d_out;
  char* ws = (char*)d_ws;

  // Workspace: q bf16 @0 (64MB) | k bf16 @64MB | vt bf16 @128MB |
  //            score f32 [8][1024][1024] @192MB (attn bf16 in-place).
  // Split-K partial (32MB fp32) lives in d_out (dead until GEMM2 overwrites).
  u16*  q      = (u16*)ws;
  u16*  k      = (u16*)(ws + 67108864);
  u16*  vt     = (u16*)(ws + 134217728);
  float* score = (float*)(ws + 201326592);
  float* part  = out;

  dim3 cg(LL / 128, CC / 64, NB);
  dwconv_qkv<<<cg, 256, 0, stream>>>(x, qw, kw, vw, q, k, vt);

  // score[b] = q[b] (1024x4096) * k[b]^T, split-K=2 -> score + part
  gemm256p<<<dim3(256), 512, 0, stream>>>(q, LL, (size_t)CC * LL,
                                          k, LL, (size_t)CC * LL,
                                          score, part, CC, (size_t)CC * CC,
                                          LL, 2, 0);

  softmax_rows<<<NB * CC, 256, 0, stream>>>(score, part);

  // out[b] = attn[b] (1024x1024 bf16, rows strided 2048 u16) * vt[b]^T
  gemm256p<<<dim3(512), 512, 0, stream>>>((const u16*)score, 2048, (size_t)CC * 2048,
                                          vt, CC, (size_t)LL * CC,
                                          out, nullptr, LL, (size_t)CC * LL,
                                          CC, 1, 1);
}

// Round 10
// 250.861 us; speedup vs baseline: 1.1009x; 1.1009x over previous
//
#include <hip/hip_runtime.h>
#include <hip/hip_bf16.h>

typedef unsigned short u16;
typedef __attribute__((ext_vector_type(8))) __bf16 bf16x8;
typedef __attribute__((ext_vector_type(4))) float f32x4;
typedef __attribute__((ext_vector_type(4))) unsigned int u32x4;

#define CC 1024
#define LL 4096
#define NB 8

#define VMCNT(n) asm volatile("s_waitcnt vmcnt(" #n ")" ::: "memory")
#define LGKMC(n) asm volatile("s_waitcnt lgkmcnt(" #n ")" ::: "memory")
#define BAR()    asm volatile("s_barrier" ::: "memory")

__device__ __forceinline__ u16 f2bf(float f) {
  union { float f; unsigned u; } v; v.f = f;
  unsigned u = v.u;
  return (u16)((u + 0x7fffu + ((u >> 16) & 1u)) >> 16);
}

// native hardware cvt (RTNE)
__device__ __forceinline__ u16 bfc(float f) {
  __bf16 h = (__bf16)f;
  return __builtin_bit_cast(u16, h);
}

__device__ __forceinline__ void gload_lds16(const void* g, void* l) {
  __builtin_amdgcn_global_load_lds(
      (const __attribute__((address_space(1))) void*)g,
      (__attribute__((address_space(3))) void*)l, 16, 0, 0);
}

// ---------------------------------------------------------------------------
// Fused depthwise conv (K=7, pad=3): q,k row-major [b,c,l] bf16, v transposed
// [b,l,c] bf16. R10: back to the R5 decomposition (64ch x 64pos tile, 16
// pos/thread, 8192 blocks — best measured latency hiding, 98us) + the R6+
// fixes: native bfc cvt, lgkm-only barrier, group-XOR swizzled transpose
// (0 bank conflicts) with b128-width LDS reads.
// ---------------------------------------------------------------------------
__global__ __launch_bounds__(256) void dwconv_qkv(
    const float* __restrict__ x, const float* __restrict__ qw,
    const float* __restrict__ kw, const float* __restrict__ vw,
    u16* __restrict__ qo, u16* __restrict__ ko, u16* __restrict__ vto)
{
  __shared__ u16 vs[64][68];
  const int t  = threadIdx.x;
  const int l0 = blockIdx.x << 6;   // 64-position tile
  const int c0 = blockIdx.y << 6;   // 64-channel tile
  const int b  = blockIdx.z;
  const int cc = t >> 2;            // channel within tile (0..63)
  const int g  = t & 3;             // 16-position group
  const int c  = c0 + cc;
  const float* xr = x + ((size_t)(b * CC + c)) * LL;
  const int li0 = g << 4;
  const int p0  = l0 + li0;

  float xv[24];                     // [p0-4, p0+20)
  if (l0 != 0 && l0 != LL - 64) {
    const float4* base = (const float4*)(xr + p0 - 4);
#pragma unroll
    for (int j = 0; j < 6; ++j) {
      float4 f = base[j];
      xv[4 * j + 0] = f.x; xv[4 * j + 1] = f.y;
      xv[4 * j + 2] = f.z; xv[4 * j + 3] = f.w;
    }
  } else {
#pragma unroll
    for (int i = 0; i < 24; ++i) {
      int gl = p0 - 4 + i;
      xv[i] = ((unsigned)gl < (unsigned)LL) ? xr[gl] : 0.f;
    }
  }

  float wq[7], wk[7], wv[7];
#pragma unroll
  for (int j = 0; j < 7; ++j) {
    wq[j] = qw[c * 7 + j]; wk[j] = kw[c * 7 + j]; wv[j] = vw[c * 7 + j];
  }

  const int wgrp = cc >> 4;
  alignas(16) u16 qv[16], kv[16];
#pragma unroll
  for (int li = 0; li < 16; ++li) {
    float aq = 0.f, ak = 0.f, av = 0.f;
#pragma unroll
    for (int j = 0; j < 7; ++j) {
      float xf = xv[li + 1 + j];    // = x[p0 + li - 3 + j]
      aq = fmaf(xf, wq[j], aq);
      ak = fmaf(xf, wk[j], ak);
      av = fmaf(xf, wv[j], av);
    }
    qv[li] = bfc(aq);
    kv[li] = bfc(ak);
    vs[li0 + li][(cc & 15) + ((wgrp ^ g) << 4)] = bfc(av);
  }
  size_t qoff = ((size_t)(b * CC + c)) * LL + p0;
  ((u32x4*)(qo + qoff))[0] = ((const u32x4*)qv)[0];
  ((u32x4*)(ko + qoff))[0] = ((const u32x4*)kv)[0];
  ((u32x4*)(qo + qoff))[1] = ((const u32x4*)qv)[1];
  ((u32x4*)(ko + qoff))[1] = ((const u32x4*)kv)[1];

  LGKMC(0);                         // v LDS writes ordered; q/k stores in flight
  BAR();
  const int q4 = t & 3;             // output 16-channel block
  const int ll = t >> 2;            // transpose-out row (0..63)
  const int sb = q4 ^ (ll >> 4);    // swizzled LDS block holding block q4
  bf16x8 v0 = *(const bf16x8*)&vs[ll][sb << 4];
  bf16x8 v1 = *(const bf16x8*)&vs[ll][(sb << 4) + 8];
  size_t voff = ((size_t)(b * LL) + l0 + ll) * CC + c0 + (q4 << 4);
  *(bf16x8*)(vto + voff)     = v0;
  *(bf16x8*)(vto + voff + 8) = v1;
}

// ---------------------------------------------------------------------------
// 256x256 NT bf16 GEMM, 4-phase/K-tile derived-waits pipeline (m201-class).
// C[m][n] = sum_k A[m][k]*B[n][k]. 512 thr = 8 waves (2M x 4N), 128x64/wave.
// BK=64; LDS = 2 dbuf x (A 256x64 + B 256x64) bf16 = 128 KB.
// One vmcnt(6) per K-tile; raw s_barrier only; XOR-swizzled staging (T2);
// setprio around MFMA clusters (T5); XCD-aware block decode (T1);
// counted lgkm waits (q1/q2 leave next-phase prefetch outstanding).
// ---------------------------------------------------------------------------
__global__ __launch_bounds__(512, 2) void gemm256p(
    const u16* __restrict__ A, int lda, size_t sA,
    const u16* __restrict__ B, int ldb, size_t sB,
    float* __restrict__ C0, float* __restrict__ C1, int ldc, size_t sC,
    int K, int ksplit, int mapmode)
{
  __shared__ alignas(16) u16 lds[65536];   // 128 KB
  const int t    = threadIdx.x;
  const int lane = t & 63, wave = t >> 6;
  const int wrow = wave >> 2, wcol = wave & 3;
  int bx, by, z;
  if (mapmode == 0) {        // GEMM1: 256 blocks; XCD x <- batch-splits {x,x+8}
    int wg = blockIdx.x; z = wg & 15; int r = wg >> 4; bx = r & 3; by = r >> 2;
  } else {                   // GEMM2: 512 blocks; XCD x <- batch x, y-fastest
    int wg = blockIdx.x; z = wg & 7; by = (wg >> 3) & 3; bx = wg >> 5;
  }
  const int bm = by << 8, bn = bx << 8;
  const int batch = (ksplit == 2) ? (z >> 1) : z;
  const int split = (ksplit == 2) ? (z & 1) : 0;
  const int Ks    = (ksplit == 2) ? (K >> 1) : K;
  const u16* Ab = A + (size_t)batch * sA + (size_t)split * Ks;
  const u16* Bb = B + (size_t)batch * sB + (size_t)split * Ks;

  // --- staging pointers: chunk c = wave*2+i covers 8 rows x 128B
  const int srow = lane >> 3;
  const int scol = ((lane & 7) ^ srow) << 3;   // pre-swizzled source col
  const u16* pA[2][2]; const u16* pB[2][2];    // [half][i]
  int dstOff[2];
#pragma unroll
  for (int i = 0; i < 2; ++i) {
    int cch = wave * 2 + i;
    dstOff[i] = cch * 1024 + lane * 16;        // byte offset within 16KB half
    pA[0][i] = Ab + (size_t)(bm + cch * 8 + srow) * lda + scol;
    pA[1][i] = pA[0][i] + (size_t)128 * lda;
    pB[0][i] = Bb + (size_t)(bn + cch * 8 + srow) * ldb + scol;
    pB[1][i] = pB[0][i] + (size_t)128 * ldb;
  }
  // dbuf d byte base = d*65536; A half h at h*16384; B at 32768 + h*16384.

#define STGH(P, h, base, koff)                                            \
  do {                                                                    \
    gload_lds16(P[h][0] + (koff), (char*)lds + (base) + dstOff[0]);       \
    gload_lds16(P[h][1] + (koff), (char*)lds + (base) + dstOff[1]);       \
  } while (0)

  // --- fragment read offsets
  const int r15 = lane & 15, kq = lane >> 4, swz = r15 & 7;
  int rowA[8], rowB[4], colK[2];
#pragma unroll
  for (int m = 0; m < 8; ++m) rowA[m] = (wrow * 128 + m * 16 + r15) * 128;
#pragma unroll
  for (int n = 0; n < 4; ++n) rowB[n] = 32768 + (wcol * 64 + n * 16 + r15) * 128;
#pragma unroll
  for (int s = 0; s < 2; ++s) colK[s] = (((s * 4 + kq) ^ swz)) << 4;

  f32x4 acc[8][4];
#pragma unroll
  for (int i = 0; i < 8; ++i)
#pragma unroll
    for (int j = 0; j < 4; ++j) acc[i][j] = f32x4{0.f, 0.f, 0.f, 0.f};

  const int NT = Ks >> 6;

  // --- prologue: tile0 -> dbuf0 (all), tile1 -> dbuf1 (A0,A1,B0)
  STGH(pA, 0, 0, 0);            STGH(pA, 1, 16384, 0);
  STGH(pB, 0, 32768, 0);        STGH(pB, 1, 49152, 0);
  STGH(pA, 0, 65536 + 0, 64);   STGH(pA, 1, 65536 + 16384, 64);
  STGH(pB, 0, 65536 + 32768, 64);
  VMCNT(6);
  BAR();

  const char* L = (const char*)lds;
  for (int tt = 0; tt < NT; ++tt) {
    const int d = tt & 1;
    const int dbase = d << 16, sbase = (d ^ 1) << 16;
    const int kN1 = (tt + 1) << 6, kN2 = (tt + 2) << 6;
    // ---- q1: reads {a0,b0} then prefetch aK1a; stage B1(t+1); MFMA (m0-3,k0)
    bf16x8 a0[4], aK1a[4], b0[4];
#pragma unroll
    for (int m = 0; m < 4; ++m) a0[m] = *(const bf16x8*)(L + dbase + rowA[m] + colK[0]);
#pragma unroll
    for (int n = 0; n < 4; ++n) b0[n] = *(const bf16x8*)(L + dbase + rowB[n] + colK[0]);
    if (tt + 1 < NT) STGH(pB, 1, sbase + 49152, kN1);
#pragma unroll
    for (int m = 0; m < 4; ++m) aK1a[m] = *(const bf16x8*)(L + dbase + rowA[m] + colK[1]);
    LGKMC(4);                          // a0,b0 forced; aK1a may stay in flight
    __builtin_amdgcn_sched_barrier(0);
    __builtin_amdgcn_s_setprio(1);
#pragma unroll
    for (int m = 0; m < 4; ++m)
#pragma unroll
      for (int n = 0; n < 4; ++n)
        acc[m][n] = __builtin_amdgcn_mfma_f32_16x16x32_bf16(a0[m], b0[n], acc[m][n], 0, 0, 0);
    __builtin_amdgcn_s_setprio(0);
    // ---- q2: reads a4 then prefetch aK1b; MFMA (m4-7, k0)
    bf16x8 a4[4], aK1b[4];
#pragma unroll
    for (int m = 0; m < 4; ++m) a4[m] = *(const bf16x8*)(L + dbase + rowA[m + 4] + colK[0]);
#pragma unroll
    for (int m = 0; m < 4; ++m) aK1b[m] = *(const bf16x8*)(L + dbase + rowA[m + 4] + colK[1]);
    LGKMC(4);                          // aK1a,a4 forced; aK1b may stay in flight
    __builtin_amdgcn_sched_barrier(0);
    __builtin_amdgcn_s_setprio(1);
#pragma unroll
    for (int m = 0; m < 4; ++m)
#pragma unroll
      for (int n = 0; n < 4; ++n)
        acc[m + 4][n] = __builtin_amdgcn_mfma_f32_16x16x32_bf16(a4[m], b0[n], acc[m + 4][n], 0, 0, 0);
    __builtin_amdgcn_s_setprio(0);
    BAR();                     // all A(t)-half0 reads forced -> q3 stage safe
    // ---- q3: B k1; stage A0(t+2) into THIS dbuf; MFMA (m0-3, k1)
    bf16x8 b1[4];
#pragma unroll
    for (int n = 0; n < 4; ++n) b1[n] = *(const bf16x8*)(L + dbase + rowB[n] + colK[1]);
    if (tt + 2 < NT) STGH(pA, 0, dbase + 0, kN2);
    LGKMC(0);                          // b1 + aK1b all complete
    __builtin_amdgcn_sched_barrier(0);
    __builtin_amdgcn_s_setprio(1);
#pragma unroll
    for (int m = 0; m < 4; ++m)
#pragma unroll
      for (int n = 0; n < 4; ++n)
        acc[m][n] = __builtin_amdgcn_mfma_f32_16x16x32_bf16(aK1a[m], b1[n], acc[m][n], 0, 0, 0);
    __builtin_amdgcn_s_setprio(0);
    BAR();                     // all B(t) reads done -> q4 stages safe
    // ---- q4: stage A1,B0(t+2); MFMA (m4-7, k1); vmcnt; barrier
    if (tt + 2 < NT) { STGH(pA, 1, dbase + 16384, kN2); STGH(pB, 0, dbase + 32768, kN2); }
    __builtin_amdgcn_s_setprio(1);
#pragma unroll
    for (int m = 0; m < 4; ++m)
#pragma unroll
      for (int n = 0; n < 4; ++n)
        acc[m + 4][n] = __builtin_amdgcn_mfma_f32_16x16x32_bf16(aK1b[m], b1[n], acc[m + 4][n], 0, 0, 0);
    __builtin_amdgcn_s_setprio(0);
    if (tt < NT - 2) { VMCNT(6); } else { VMCNT(0); }
    BAR();                     // tile t+1 fully landed before next q1 reads
  }
#undef STGH

  float* Cb = (split ? C1 : C0) + (size_t)batch * sC;
  const int row0 = bm + wrow * 128 + kq * 4;
  const int col0 = bn + wcol * 64 + r15;
#pragma unroll
  for (int m = 0; m < 8; ++m)
#pragma unroll
    for (int n = 0; n < 4; ++n) {
      const int r   = row0 + m * 16;
      const int col = col0 + n * 16;
#pragma unroll
      for (int rr = 0; rr < 4; ++rr)
        Cb[(size_t)(r + rr) * ldc + col] = acc[m][n][rr];
    }
}

// ---------------------------------------------------------------------------
// Row softmax over fp32 [8192][1024]: sums split-K partials, scales 1/sqrt(C),
// writes bf16 attn in place (row stride stays 4096 B = 2048 u16).
// ---------------------------------------------------------------------------
__global__ __launch_bounds__(256) void softmax_rows(
    float* __restrict__ score, const float* __restrict__ part)
{
  __shared__ float rmax[4], rsum[4];
  const int t = threadIdx.x;
  const int lane = t & 63, wv = t >> 6;
  float* sp = score + ((size_t)blockIdx.x << 10);
  const float* pp = part + ((size_t)blockIdx.x << 10);
  float4 v = ((const float4*)sp)[t];
  float4 w = ((const float4*)pp)[t];
  const float scale = 0.03125f;   // 1/sqrt(1024)
  float a0 = (v.x + w.x) * scale, a1 = (v.y + w.y) * scale;
  float a2 = (v.z + w.z) * scale, a3 = (v.w + w.w) * scale;
  float m = fmaxf(fmaxf(a0, a1), fmaxf(a2, a3));
#pragma unroll
  for (int o = 1; o < 64; o <<= 1) m = fmaxf(m, __shfl_xor(m, o, 64));
  if (lane == 0) rmax[wv] = m;
  __syncthreads();
  m = fmaxf(fmaxf(rmax[0], rmax[1]), fmaxf(rmax[2], rmax[3]));
  float e0 = __expf(a0 - m), e1 = __expf(a1 - m);
  float e2 = __expf(a2 - m), e3 = __expf(a3 - m);
  float s = e0 + e1 + e2 + e3;
#pragma unroll
  for (int o = 1; o < 64; o <<= 1) s += __shfl_xor(s, o, 64);
  if (lane == 0) rsum[wv] = s;
  __syncthreads();
  s = rsum[0] + rsum[1] + rsum[2] + rsum[3];
  const float inv = 1.0f / s;
  union { u16 u[4]; uint2 p; } ob;
  ob.u[0] = f2bf(e0 * inv); ob.u[1] = f2bf(e1 * inv);
  ob.u[2] = f2bf(e2 * inv); ob.u[3] = f2bf(e3 * inv);
  *(uint2*)((u16*)sp + (t << 2)) = ob.p;
}

// ---------------------------------------------------------------------------
extern "C" void kernel_launch(void* const* d_in, const int* in_sizes, int n_in,
                              void* d_out, int out_size, void* d_ws, size_t ws_size,
                              hipStream_t stream) {
  const float* x  = (const float*)d_in[0];
  const float* qw = (const float*)d_in[1];
  const float* kw = (const float*)d_in[2];
  const float* vw = (const float*)d_in[3];
  float* out = (float*)d_out;
  char* ws = (char*)d_ws;

  // Workspace: q bf16 @0 (64MB) | k bf16 @64MB | vt bf16 @128MB |
  //            score f32 [8][1024][1024] @192MB (attn bf16 in-place).
  // Split-K partial (32MB fp32) lives in d_out (dead until GEMM2 overwrites).
  u16*  q      = (u16*)ws;
  u16*  k      = (u16*)(ws + 67108864);
  u16*  vt     = (u16*)(ws + 134217728);
  float* score = (float*)(ws + 201326592);
  float* part  = out;

  dim3 cg(LL / 64, CC / 64, NB);
  dwconv_qkv<<<cg, 256, 0, stream>>>(x, qw, kw, vw, q, k, vt);

  // score[b] = q[b] (1024x4096) * k[b]^T, split-K=2 -> score + part
  gemm256p<<<dim3(256), 512, 0, stream>>>(q, LL, (size_t)CC * LL,
                                          k, LL, (size_t)CC * LL,
                                          score, part, CC, (size_t)CC * CC,
                                          LL, 2, 0);

  softmax_rows<<<NB * CC, 256, 0, stream>>>(score, part);

  // out[b] = attn[b] (1024x1024 bf16, rows strided 2048 u16) * vt[b]^T
  gemm256p<<<dim3(512), 512, 0, stream>>>((const u16*)score, 2048, (size_t)CC * 2048,
                                          vt, CC, (size_t)LL * CC,
                                          out, nullptr, LL, (size_t)CC * LL,
                                          CC, 1, 1);
}

// Round 13
// 240.772 us; speedup vs baseline: 1.1470x; 1.0419x over previous
//
#include <hip/hip_runtime.h>
#include <hip/hip_bf16.h>

typedef unsigned short u16;
typedef unsigned int u32;
typedef __attribute__((ext_vector_type(8))) __bf16 bf16x8;
typedef __attribute__((ext_vector_type(4))) float f32x4;
typedef __attribute__((ext_vector_type(4))) unsigned int u32x4;

#define CC 1024
#define LL 4096
#define NB 8

#define VMCNT(n) asm volatile("s_waitcnt vmcnt(" #n ")" ::: "memory")
#define LGKMC(n) asm volatile("s_waitcnt lgkmcnt(" #n ")" ::: "memory")
#define BAR()    asm volatile("s_barrier" ::: "memory")

__device__ __forceinline__ u16 f2bf(float f) {
  union { float f; unsigned u; } v; v.f = f;
  unsigned u = v.u;
  return (u16)((u + 0x7fffu + ((u >> 16) & 1u)) >> 16);
}

// native hardware cvt (RTNE)
__device__ __forceinline__ u16 bfc(float f) {
  __bf16 h = (__bf16)f;
  return __builtin_bit_cast(u16, h);
}

__device__ __forceinline__ float bf2f(u32 u) {
  return __builtin_bit_cast(float, u << 16);
}

__device__ __forceinline__ void gload_lds16(const void* g, void* l) {
  __builtin_amdgcn_global_load_lds(
      (const __attribute__((address_space(1))) void*)g,
      (__attribute__((address_space(3))) void*)l, 16, 0, 0);
}

// ---------------------------------------------------------------------------
// Fused depthwise conv (K=7, pad=3): q,k row-major [b,c,l] bf16, v transposed
// [b,l,c] bf16. 64ch x 64pos tile, 16 pos/thread (R10 measured-best shape).
// Group-XOR swizzled LDS transpose (0 conflicts); lgkm-only barrier.
// ---------------------------------------------------------------------------
__global__ __launch_bounds__(256) void dwconv_qkv(
    const float* __restrict__ x, const float* __restrict__ qw,
    const float* __restrict__ kw, const float* __restrict__ vw,
    u16* __restrict__ qo, u16* __restrict__ ko, u16* __restrict__ vto)
{
  __shared__ u16 vs[64][68];
  const int t  = threadIdx.x;
  const int l0 = blockIdx.x << 6;   // 64-position tile
  const int c0 = blockIdx.y << 6;   // 64-channel tile
  const int b  = blockIdx.z;
  const int cc = t >> 2;            // channel within tile (0..63)
  const int g  = t & 3;             // 16-position group
  const int c  = c0 + cc;
  const float* xr = x + ((size_t)(b * CC + c)) * LL;
  const int li0 = g << 4;
  const int p0  = l0 + li0;

  float xv[24];                     // [p0-4, p0+20)
  if (l0 != 0 && l0 != LL - 64) {
    const float4* base = (const float4*)(xr + p0 - 4);
#pragma unroll
    for (int j = 0; j < 6; ++j) {
      float4 f = base[j];
      xv[4 * j + 0] = f.x; xv[4 * j + 1] = f.y;
      xv[4 * j + 2] = f.z; xv[4 * j + 3] = f.w;
    }
  } else {
#pragma unroll
    for (int i = 0; i < 24; ++i) {
      int gl = p0 - 4 + i;
      xv[i] = ((unsigned)gl < (unsigned)LL) ? xr[gl] : 0.f;
    }
  }

  float wq[7], wk[7], wv[7];
#pragma unroll
  for (int j = 0; j < 7; ++j) {
    wq[j] = qw[c * 7 + j]; wk[j] = kw[c * 7 + j]; wv[j] = vw[c * 7 + j];
  }

  const int wgrp = cc >> 4;
  alignas(16) u16 qv[16], kv[16];
#pragma unroll
  for (int li = 0; li < 16; ++li) {
    float aq = 0.f, ak = 0.f, av = 0.f;
#pragma unroll
    for (int j = 0; j < 7; ++j) {
      float xf = xv[li + 1 + j];    // = x[p0 + li - 3 + j]
      aq = fmaf(xf, wq[j], aq);
      ak = fmaf(xf, wk[j], ak);
      av = fmaf(xf, wv[j], av);
    }
    qv[li] = bfc(aq);
    kv[li] = bfc(ak);
    vs[li0 + li][(cc & 15) + ((wgrp ^ g) << 4)] = bfc(av);
  }
  size_t qoff = ((size_t)(b * CC + c)) * LL + p0;
  ((u32x4*)(qo + qoff))[0] = ((const u32x4*)qv)[0];
  ((u32x4*)(ko + qoff))[0] = ((const u32x4*)kv)[0];
  ((u32x4*)(qo + qoff))[1] = ((const u32x4*)qv)[1];
  ((u32x4*)(ko + qoff))[1] = ((const u32x4*)kv)[1];

  LGKMC(0);                         // v LDS writes ordered; q/k stores in flight
  BAR();
  const int q4 = t & 3;             // output 16-channel block
  const int ll = t >> 2;            // transpose-out row (0..63)
  const int sb = q4 ^ (ll >> 4);    // swizzled LDS block holding block q4
  bf16x8 v0 = *(const bf16x8*)&vs[ll][sb << 4];
  bf16x8 v1 = *(const bf16x8*)&vs[ll][(sb << 4) + 8];
  size_t voff = ((size_t)(b * LL) + l0 + ll) * CC + c0 + (q4 << 4);
  *(bf16x8*)(vto + voff)     = v0;
  *(bf16x8*)(vto + voff + 8) = v1;
}

// ---------------------------------------------------------------------------
// 256x256 NT bf16 GEMM, 4-phase/K-tile derived-waits pipeline (m201-class).
// C[m][n] = sum_k A[m][k]*B[n][k]. 512 thr = 8 waves (2M x 4N), 128x64/wave.
// BK=64; LDS = 2 dbuf x (A 256x64 + B 256x64) bf16 = 128 KB.
// One vmcnt(6) per K-tile; raw s_barrier only; XOR-swizzled staging (T2);
// setprio around MFMA clusters (T5); XCD-aware block decode (T1);
// counted lgkm waits. obf16: write C as bf16 (for the score/partials).
// ---------------------------------------------------------------------------
__global__ __launch_bounds__(512, 2) void gemm256p(
    const u16* __restrict__ A, int lda, size_t sA,
    const u16* __restrict__ B, int ldb, size_t sB,
    void* __restrict__ C0, void* __restrict__ C1, int ldc, size_t sC,
    int K, int ksplit, int mapmode, int obf16)
{
  __shared__ alignas(16) u16 lds[65536];   // 128 KB
  const int t    = threadIdx.x;
  const int lane = t & 63, wave = t >> 6;
  const int wrow = wave >> 2, wcol = wave & 3;
  int bx, by, z;
  if (mapmode == 0) {        // GEMM1: 256 blocks; XCD x <- batch-splits {x,x+8}
    int wg = blockIdx.x; z = wg & 15; int r = wg >> 4; bx = r & 3; by = r >> 2;
  } else {                   // GEMM2: 512 blocks; XCD x <- batch x, y-fastest
    int wg = blockIdx.x; z = wg & 7; by = (wg >> 3) & 3; bx = wg >> 5;
  }
  const int bm = by << 8, bn = bx << 8;
  const int batch = (ksplit == 2) ? (z >> 1) : z;
  const int split = (ksplit == 2) ? (z & 1) : 0;
  const int Ks    = (ksplit == 2) ? (K >> 1) : K;
  const u16* Ab = A + (size_t)batch * sA + (size_t)split * Ks;
  const u16* Bb = B + (size_t)batch * sB + (size_t)split * Ks;

  // --- staging pointers: chunk c = wave*2+i covers 8 rows x 128B
  const int srow = lane >> 3;
  const int scol = ((lane & 7) ^ srow) << 3;   // pre-swizzled source col
  const u16* pA[2][2]; const u16* pB[2][2];    // [half][i]
  int dstOff[2];
#pragma unroll
  for (int i = 0; i < 2; ++i) {
    int cch = wave * 2 + i;
    dstOff[i] = cch * 1024 + lane * 16;        // byte offset within 16KB half
    pA[0][i] = Ab + (size_t)(bm + cch * 8 + srow) * lda + scol;
    pA[1][i] = pA[0][i] + (size_t)128 * lda;
    pB[0][i] = Bb + (size_t)(bn + cch * 8 + srow) * ldb + scol;
    pB[1][i] = pB[0][i] + (size_t)128 * ldb;
  }
  // dbuf d byte base = d*65536; A half h at h*16384; B at 32768 + h*16384.

#define STGH(P, h, base, koff)                                            \
  do {                                                                    \
    gload_lds16(P[h][0] + (koff), (char*)lds + (base) + dstOff[0]);       \
    gload_lds16(P[h][1] + (koff), (char*)lds + (base) + dstOff[1]);       \
  } while (0)

  // --- fragment read offsets
  const int r15 = lane & 15, kq = lane >> 4, swz = r15 & 7;
  int rowA[8], rowB[4], colK[2];
#pragma unroll
  for (int m = 0; m < 8; ++m) rowA[m] = (wrow * 128 + m * 16 + r15) * 128;
#pragma unroll
  for (int n = 0; n < 4; ++n) rowB[n] = 32768 + (wcol * 64 + n * 16 + r15) * 128;
#pragma unroll
  for (int s = 0; s < 2; ++s) colK[s] = (((s * 4 + kq) ^ swz)) << 4;

  f32x4 acc[8][4];
#pragma unroll
  for (int i = 0; i < 8; ++i)
#pragma unroll
    for (int j = 0; j < 4; ++j) acc[i][j] = f32x4{0.f, 0.f, 0.f, 0.f};

  const int NT = Ks >> 6;

  // --- prologue: tile0 -> dbuf0 (all), tile1 -> dbuf1 (A0,A1,B0)
  STGH(pA, 0, 0, 0);            STGH(pA, 1, 16384, 0);
  STGH(pB, 0, 32768, 0);        STGH(pB, 1, 49152, 0);
  STGH(pA, 0, 65536 + 0, 64);   STGH(pA, 1, 65536 + 16384, 64);
  STGH(pB, 0, 65536 + 32768, 64);
  VMCNT(6);
  BAR();

  const char* L = (const char*)lds;
  for (int tt = 0; tt < NT; ++tt) {
    const int d = tt & 1;
    const int dbase = d << 16, sbase = (d ^ 1) << 16;
    const int kN1 = (tt + 1) << 6, kN2 = (tt + 2) << 6;
    // ---- q1: reads {a0,b0} then prefetch aK1a; stage B1(t+1); MFMA (m0-3,k0)
    bf16x8 a0[4], aK1a[4], b0[4];
#pragma unroll
    for (int m = 0; m < 4; ++m) a0[m] = *(const bf16x8*)(L + dbase + rowA[m] + colK[0]);
#pragma unroll
    for (int n = 0; n < 4; ++n) b0[n] = *(const bf16x8*)(L + dbase + rowB[n] + colK[0]);
    if (tt + 1 < NT) STGH(pB, 1, sbase + 49152, kN1);
#pragma unroll
    for (int m = 0; m < 4; ++m) aK1a[m] = *(const bf16x8*)(L + dbase + rowA[m] + colK[1]);
    LGKMC(4);                          // a0,b0 forced; aK1a may stay in flight
    __builtin_amdgcn_sched_barrier(0);
    __builtin_amdgcn_s_setprio(1);
#pragma unroll
    for (int m = 0; m < 4; ++m)
#pragma unroll
      for (int n = 0; n < 4; ++n)
        acc[m][n] = __builtin_amdgcn_mfma_f32_16x16x32_bf16(a0[m], b0[n], acc[m][n], 0, 0, 0);
    __builtin_amdgcn_s_setprio(0);
    // ---- q2: reads a4 then prefetch aK1b; MFMA (m4-7, k0)
    bf16x8 a4[4], aK1b[4];
#pragma unroll
    for (int m = 0; m < 4; ++m) a4[m] = *(const bf16x8*)(L + dbase + rowA[m + 4] + colK[0]);
#pragma unroll
    for (int m = 0; m < 4; ++m) aK1b[m] = *(const bf16x8*)(L + dbase + rowA[m + 4] + colK[1]);
    LGKMC(4);                          // aK1a,a4 forced; aK1b may stay in flight
    __builtin_amdgcn_sched_barrier(0);
    __builtin_amdgcn_s_setprio(1);
#pragma unroll
    for (int m = 0; m < 4; ++m)
#pragma unroll
      for (int n = 0; n < 4; ++n)
        acc[m + 4][n] = __builtin_amdgcn_mfma_f32_16x16x32_bf16(a4[m], b0[n], acc[m + 4][n], 0, 0, 0);
    __builtin_amdgcn_s_setprio(0);
    BAR();                     // all A(t)-half0 reads forced -> q3 stage safe
    // ---- q3: B k1; stage A0(t+2) into THIS dbuf; MFMA (m0-3, k1)
    bf16x8 b1[4];
#pragma unroll
    for (int n = 0; n < 4; ++n) b1[n] = *(const bf16x8*)(L + dbase + rowB[n] + colK[1]);
    if (tt + 2 < NT) STGH(pA, 0, dbase + 0, kN2);
    LGKMC(0);                          // b1 + aK1b all complete
    __builtin_amdgcn_sched_barrier(0);
    __builtin_amdgcn_s_setprio(1);
#pragma unroll
    for (int m = 0; m < 4; ++m)
#pragma unroll
      for (int n = 0; n < 4; ++n)
        acc[m][n] = __builtin_amdgcn_mfma_f32_16x16x32_bf16(aK1a[m], b1[n], acc[m][n], 0, 0, 0);
    __builtin_amdgcn_s_setprio(0);
    BAR();                     // all B(t) reads done -> q4 stages safe
    // ---- q4: stage A1,B0(t+2); MFMA (m4-7, k1); vmcnt; barrier
    if (tt + 2 < NT) { STGH(pA, 1, dbase + 16384, kN2); STGH(pB, 0, dbase + 32768, kN2); }
    __builtin_amdgcn_s_setprio(1);
#pragma unroll
    for (int m = 0; m < 4; ++m)
#pragma unroll
      for (int n = 0; n < 4; ++n)
        acc[m + 4][n] = __builtin_amdgcn_mfma_f32_16x16x32_bf16(aK1b[m], b1[n], acc[m + 4][n], 0, 0, 0);
    __builtin_amdgcn_s_setprio(0);
    if (tt < NT - 2) { VMCNT(6); } else { VMCNT(0); }
    BAR();                     // tile t+1 fully landed before next q1 reads
  }
#undef STGH

  const int row0 = bm + wrow * 128 + kq * 4;
  const int col0 = bn + wcol * 64 + r15;
  if (obf16) {
    u16* Cb = (u16*)(split ? C1 : C0) + (size_t)batch * sC;
#pragma unroll
    for (int m = 0; m < 8; ++m)
#pragma unroll
      for (int n = 0; n < 4; ++n) {
        const int r   = row0 + m * 16;
        const int col = col0 + n * 16;
#pragma unroll
        for (int rr = 0; rr < 4; ++rr)
          Cb[(size_t)(r + rr) * ldc + col] = bfc(acc[m][n][rr]);
      }
  } else {
    float* Cb = (float*)(split ? C1 : C0) + (size_t)batch * sC;
#pragma unroll
    for (int m = 0; m < 8; ++m)
#pragma unroll
      for (int n = 0; n < 4; ++n) {
        const int r   = row0 + m * 16;
        const int col = col0 + n * 16;
#pragma unroll
        for (int rr = 0; rr < 4; ++rr)
          Cb[(size_t)(r + rr) * ldc + col] = acc[m][n][rr];
      }
  }
}

// ---------------------------------------------------------------------------
// Row softmax over bf16 [8192][1024]: sums two bf16 split-K partials, scales
// by 1/sqrt(C), writes bf16 attn in place over the score rows (stride 1024).
// ---------------------------------------------------------------------------
__global__ __launch_bounds__(256) void softmax_rows(
    u16* __restrict__ score, const u16* __restrict__ part)
{
  __shared__ float rmax[4], rsum[4];
  const int t = threadIdx.x;
  const int lane = t & 63, wv = t >> 6;
  u16* sp = score + ((size_t)blockIdx.x << 10);
  const u16* pp = part + ((size_t)blockIdx.x << 10);
  uint2 va = *(const uint2*)(sp + (t << 2));
  uint2 vb = *(const uint2*)(pp + (t << 2));
  const float scale = 0.03125f;   // 1/sqrt(1024)
  float a0 = (bf2f(va.x & 0xffffu) + bf2f(vb.x & 0xffffu)) * scale;
  float a1 = (bf2f(va.x >> 16)     + bf2f(vb.x >> 16))     * scale;
  float a2 = (bf2f(va.y & 0xffffu) + bf2f(vb.y & 0xffffu)) * scale;
  float a3 = (bf2f(va.y >> 16)     + bf2f(vb.y >> 16))     * scale;
  float m = fmaxf(fmaxf(a0, a1), fmaxf(a2, a3));
#pragma unroll
  for (int o = 1; o < 64; o <<= 1) m = fmaxf(m, __shfl_xor(m, o, 64));
  if (lane == 0) rmax[wv] = m;
  __syncthreads();
  m = fmaxf(fmaxf(rmax[0], rmax[1]), fmaxf(rmax[2], rmax[3]));
  float e0 = __expf(a0 - m), e1 = __expf(a1 - m);
  float e2 = __expf(a2 - m), e3 = __expf(a3 - m);
  float s = e0 + e1 + e2 + e3;
#pragma unroll
  for (int o = 1; o < 64; o <<= 1) s += __shfl_xor(s, o, 64);
  if (lane == 0) rsum[wv] = s;
  __syncthreads();
  s = rsum[0] + rsum[1] + rsum[2] + rsum[3];
  const float inv = 1.0f / s;
  uint2 ob;
  ob.x = (u32)f2bf(e0 * inv) | ((u32)f2bf(e1 * inv) << 16);
  ob.y = (u32)f2bf(e2 * inv) | ((u32)f2bf(e3 * inv) << 16);
  *(uint2*)(sp + (t << 2)) = ob;   // in-place; this thread owns these 4 elems
}

// ---------------------------------------------------------------------------
extern "C" void kernel_launch(void* const* d_in, const int* in_sizes, int n_in,
                              void* d_out, int out_size, void* d_ws, size_t ws_size,
                              hipStream_t stream) {
  const float* x  = (const float*)d_in[0];
  const float* qw = (const float*)d_in[1];
  const float* kw = (const float*)d_in[2];
  const float* vw = (const float*)d_in[3];
  float* out = (float*)d_out;
  char* ws = (char*)d_ws;

  // Workspace: q bf16 @0 (64MB) | k bf16 @64MB | vt bf16 @128MB |
  //            score bf16 [8][1024][1024] @192MB (16MB; attn in-place).
  // Split-K partial (16MB bf16) lives in d_out (dead until GEMM2 overwrites).
  u16*  q     = (u16*)ws;
  u16*  k     = (u16*)(ws + 67108864);
  u16*  vt    = (u16*)(ws + 134217728);
  u16*  score = (u16*)(ws + 201326592);
  u16*  part  = (u16*)d_out;

  dim3 cg(LL / 64, CC / 64, NB);
  dwconv_qkv<<<cg, 256, 0, stream>>>(x, qw, kw, vw, q, k, vt);

  // score[b] = q[b] (1024x4096) * k[b]^T, split-K=2, bf16 out -> score + part
  gemm256p<<<dim3(256), 512, 0, stream>>>(q, LL, (size_t)CC * LL,
                                          k, LL, (size_t)CC * LL,
                                          (void*)score, (void*)part,
                                          CC, (size_t)CC * CC,
                                          LL, 2, 0, 1);

  softmax_rows<<<NB * CC, 256, 0, stream>>>(score, part);

  // out[b] = attn[b] (1024x1024 bf16, row stride 1024) * vt[b]^T, fp32 out
  gemm256p<<<dim3(512), 512, 0, stream>>>(score, CC, (size_t)CC * CC,
                                          vt, CC, (size_t)LL * CC,
                                          (void*)out, nullptr,
                                          LL, (size_t)CC * LL,
                                          CC, 1, 1, 0);
}